// Round 4
// baseline (259.625 us; speedup 1.0000x reference)
//
#include <hip/hip_runtime.h>
#include <hip/hip_bf16.h>

#define LL 512
#define BB 32
#define DD 256
#define NS 16
#define RK 16
#define CH 16          // chunks over L
#define LC 32          // L per chunk

typedef __attribute__((ext_vector_type(8))) short bf16x8;
typedef __attribute__((ext_vector_type(4))) float f32x4;

// load 16 consecutive floats into a scalar array (float4 x4)
#define LD16(dst, src, off) { \
  float4 _v0 = *reinterpret_cast<const float4*>(&(src)[(off)]); \
  float4 _v1 = *reinterpret_cast<const float4*>(&(src)[(off)+4]); \
  float4 _v2 = *reinterpret_cast<const float4*>(&(src)[(off)+8]); \
  float4 _v3 = *reinterpret_cast<const float4*>(&(src)[(off)+12]); \
  dst[0]=_v0.x; dst[1]=_v0.y; dst[2]=_v0.z; dst[3]=_v0.w; \
  dst[4]=_v1.x; dst[5]=_v1.y; dst[6]=_v1.z; dst[7]=_v1.w; \
  dst[8]=_v2.x; dst[9]=_v2.y; dst[10]=_v2.z; dst[11]=_v2.w; \
  dst[12]=_v3.x; dst[13]=_v3.y; dst[14]=_v3.z; dst[15]=_v3.w; }

static __device__ __forceinline__ unsigned short f2bf(float x) {
    __hip_bfloat16 h = __float2bfloat16(x);
    return *reinterpret_cast<unsigned short*>(&h);
}

// ---------------- K0: W -> bf16 ----------------
__global__ __launch_bounds__(256) void k0_wbf(
    const float* __restrict__ W, unsigned short* __restrict__ Wbf)
{
    int i = (blockIdx.x * 256 + threadIdx.x) * 4;
    float4 v = *reinterpret_cast<const float4*>(&W[i]);
    ushort4 o;
    o.x = f2bf(v.x); o.y = f2bf(v.y); o.z = f2bf(v.z); o.w = f2bf(v.w);
    *reinterpret_cast<ushort4*>(&Wbf[i]) = o;
}

// ---------------- K1: projections ----------------
// block: 32 rows.
// stage1: thread (r=tid>>3, cg=tid&7) computes x_dbl[r][cg*6..+5]
//   flow row from LDS (broadcast within 8-lane groups, banks conflict-free),
//   W via global loads (48KB, L1/L2 resident).
// stage2: thread d computes delta for 32 rows (sdbl reads wave-uniform broadcast).
__global__ __launch_bounds__(256) void k1_proj(
    const float* __restrict__ flow,       // (L,B,D)
    const float* __restrict__ x_proj_w,   // (48,D)
    const float* __restrict__ dt_w,       // (D,RK)
    const float* __restrict__ dt_b,       // (D)
    float* __restrict__ delta,            // (B,L,D)
    float* __restrict__ Bm,               // (B,L,NS)
    float* __restrict__ Cm)               // (B,L,NS)
{
    const int ROWS = 32;
    const int FP = 260;                   // sflow row pad (floats); stride%32==4
    const int SP = 52;                    // sdbl row pad
    __shared__ float sflow[ROWS * FP];    // 33.3 KB
    __shared__ float sdbl[ROWS * SP];     // 6.7 KB
    int tid = threadIdx.x;
    int row0 = blockIdx.x * ROWS;         // row = b*512 + l

    // stage flow rows: 32 rows x 64 float4 = 2048 slots, 8 iters x 256 threads
    #pragma unroll
    for (int jj = 0; jj < 8; ++jj) {
        int s = tid + jj * 256;           // 0..2047
        int r = s >> 6, c4 = s & 63;
        int row = row0 + r;
        int b = row >> 9, l = row & 511;
        float4 v = *reinterpret_cast<const float4*>(&flow[(l * BB + b) * DD + c4 * 4]);
        *reinterpret_cast<float4*>(&sflow[r * FP + c4 * 4]) = v;
    }
    __syncthreads();

    // stage 1: x_dbl[r][cg*6 .. cg*6+5]
    {
        int r = tid >> 3, cg = tid & 7;   // 8 lanes share a row -> LDS broadcast
        float acc6[6] = {};
        const float* frow = &sflow[r * FP];
        for (int k = 0; k < DD; k += 4) {
            float4 fv = *reinterpret_cast<const float4*>(&frow[k]);
            #pragma unroll
            for (int j = 0; j < 6; ++j) {
                float4 wv = *reinterpret_cast<const float4*>(&x_proj_w[(cg * 6 + j) * DD + k]);
                acc6[j] = fmaf(fv.x, wv.x, acc6[j]);
                acc6[j] = fmaf(fv.y, wv.y, acc6[j]);
                acc6[j] = fmaf(fv.z, wv.z, acc6[j]);
                acc6[j] = fmaf(fv.w, wv.w, acc6[j]);
            }
        }
        #pragma unroll
        for (int j = 0; j < 6; ++j) sdbl[r * SP + cg * 6 + j] = acc6[j];
    }
    __syncthreads();

    // B/C copy out (coalesced)
    #pragma unroll
    for (int jj = 0; jj < 2; ++jj) {
        int idx = tid + jj * 256;         // 512 elems
        int r = idx >> 4, c = idx & 15;
        Bm[(row0 + r) * NS + c] = sdbl[r * SP + RK + c];
        Cm[(row0 + r) * NS + c] = sdbl[r * SP + RK + NS + c];
    }

    // stage 2: delta = softplus(dr @ dtw.T + b), thread d = tid
    float wreg[RK];
    #pragma unroll
    for (int k = 0; k < RK; k += 4) {
        float4 v = *reinterpret_cast<const float4*>(&dt_w[tid * RK + k]);
        wreg[k] = v.x; wreg[k + 1] = v.y; wreg[k + 2] = v.z; wreg[k + 3] = v.w;
    }
    float bias = dt_b[tid];
    for (int r = 0; r < ROWS; ++r) {
        const float* srow = &sdbl[r * SP];
        float s = bias;
        #pragma unroll
        for (int k = 0; k < RK; ++k) s = fmaf(srow[k], wreg[k], s);
        float sp = fmaxf(s, 0.f) + log1pf(__expf(-fabsf(s)));
        delta[(size_t)(row0 + r) * DD + tid] = sp;
    }
}

// ---------------- K2 pass A: per-chunk local scan ----------------
__global__ __launch_bounds__(256) void k2_scanA(
    const float* __restrict__ u_pos,    // (L,B,D)
    const float* __restrict__ A_log,    // (D,NS)
    const float* __restrict__ delta,    // (B,L,D)
    const float* __restrict__ Bm,       // (B,L,NS)
    float* __restrict__ aprod,          // (B,CH,D,NS)
    float* __restrict__ hpart)          // (B,CH,D,NS)
{
    int b = blockIdx.x >> 4;
    int c = blockIdx.x & 15;
    int d = threadIdx.x;
    int l0 = c * LC;

    float a[NS];
    #pragma unroll
    for (int n = 0; n < NS; n += 4) {
        float4 v = *reinterpret_cast<const float4*>(&A_log[d * NS + n]);
        a[n]     = -__expf(v.x) * 1.44269504f;   // dA = exp2(dlt*a)
        a[n + 1] = -__expf(v.y) * 1.44269504f;
        a[n + 2] = -__expf(v.z) * 1.44269504f;
        a[n + 3] = -__expf(v.w) * 1.44269504f;
    }
    float h[NS], ap[NS];
    #pragma unroll
    for (int n = 0; n < NS; ++n) { h[n] = 0.f; ap[n] = 1.f; }

    const float* dp = delta + ((size_t)b * LL + l0) * DD + d;
    const float* up = u_pos + ((size_t)l0 * BB + b) * DD + d;
    const float* Bp = Bm + ((size_t)b * LL + l0) * NS;

    for (int l = 0; l < LC; l += 2) {
        float d0 = dp[l * DD],        d1 = dp[(l + 1) * DD];
        float u0 = up[l * BB * DD],   u1 = up[(l + 1) * BB * DD];
        float B0[NS], B1[NS];
        LD16(B0, Bp, l * NS);
        LD16(B1, Bp, (l + 1) * NS);
        float du0 = d0 * u0, du1 = d1 * u1;
        #pragma unroll
        for (int n = 0; n < NS; ++n) {
            float dA = exp2f(d0 * a[n]);
            ap[n] *= dA;
            h[n] = fmaf(dA, h[n], du0 * B0[n]);
        }
        #pragma unroll
        for (int n = 0; n < NS; ++n) {
            float dA = exp2f(d1 * a[n]);
            ap[n] *= dA;
            h[n] = fmaf(dA, h[n], du1 * B1[n]);
        }
    }

    size_t o = (((size_t)b * CH + c) * DD + d) * NS;
    #pragma unroll
    for (int n = 0; n < NS; n += 4) {
        *reinterpret_cast<float4*>(&aprod[o + n]) = make_float4(ap[n], ap[n+1], ap[n+2], ap[n+3]);
        *reinterpret_cast<float4*>(&hpart[o + n]) = make_float4(h[n], h[n+1], h[n+2], h[n+3]);
    }
}

// ---------------- K2 pass B: combine chunks ----------------
__global__ __launch_bounds__(256) void k2_scanB(
    const float* __restrict__ h0,       // (B,D,NS)
    const float* __restrict__ aprod,
    float* __restrict__ hpart,          // in: local results; out: h_in per chunk
    float* __restrict__ h_out)          // (B,D,NS)
{
    int t = blockIdx.x * 256 + threadIdx.x;
    float s = h0[t];
    int b = t >> 12, dn = t & 4095;
    for (int c = 0; c < CH; ++c) {
        size_t idx = ((size_t)(b * CH + c) << 12) + dn;
        float apv = aprod[idx];
        float hpv = hpart[idx];
        hpart[idx] = s;
        s = fmaf(apv, s, hpv);
    }
    h_out[t] = s;
}

// ---------------- K2 pass C: re-scan with true h_in, emit y (bf16) ----------------
__global__ __launch_bounds__(256) void k2_scanC(
    const float* __restrict__ u_pos,
    const float* __restrict__ A_log,
    const float* __restrict__ Dp,
    const float* __restrict__ delta,
    const float* __restrict__ Bm,
    const float* __restrict__ Cm,
    const float* __restrict__ hpart,    // h_in per chunk
    unsigned short* __restrict__ ybf)   // (B,L,D) bf16
{
    int b = blockIdx.x >> 4;
    int c = blockIdx.x & 15;
    int d = threadIdx.x;
    int l0 = c * LC;

    float a[NS];
    #pragma unroll
    for (int n = 0; n < NS; n += 4) {
        float4 v = *reinterpret_cast<const float4*>(&A_log[d * NS + n]);
        a[n]     = -__expf(v.x) * 1.44269504f;
        a[n + 1] = -__expf(v.y) * 1.44269504f;
        a[n + 2] = -__expf(v.z) * 1.44269504f;
        a[n + 3] = -__expf(v.w) * 1.44269504f;
    }
    float h[NS];
    {
        size_t o = (((size_t)b * CH + c) * DD + d) * NS;
        LD16(h, hpart, o);
    }
    float Dd = Dp[d];

    const float* dp = delta + ((size_t)b * LL + l0) * DD + d;
    const float* up = u_pos + ((size_t)l0 * BB + b) * DD + d;
    const float* Bp = Bm + ((size_t)b * LL + l0) * NS;
    const float* Cp = Cm + ((size_t)b * LL + l0) * NS;
    unsigned short* yp = ybf + ((size_t)b * LL + l0) * DD + d;

    for (int l = 0; l < LC; l += 2) {
        float d0 = dp[l * DD],        d1 = dp[(l + 1) * DD];
        float u0 = up[l * BB * DD],   u1 = up[(l + 1) * BB * DD];
        float B0[NS], B1[NS], C0[NS], C1[NS];
        LD16(B0, Bp, l * NS);
        LD16(B1, Bp, (l + 1) * NS);
        LD16(C0, Cp, l * NS);
        LD16(C1, Cp, (l + 1) * NS);

        float du0 = d0 * u0, du1 = d1 * u1;
        float acc0 = 0.f, acc1 = 0.f;
        #pragma unroll
        for (int n = 0; n < NS; ++n) {
            float dA = exp2f(d0 * a[n]);
            h[n] = fmaf(dA, h[n], du0 * B0[n]);
            acc0 = fmaf(h[n], C0[n], acc0);
        }
        #pragma unroll
        for (int n = 0; n < NS; ++n) {
            float dA = exp2f(d1 * a[n]);
            h[n] = fmaf(dA, h[n], du1 * B1[n]);
            acc1 = fmaf(h[n], C1[n], acc1);
        }
        yp[l * DD]       = f2bf(fmaf(u0, Dd, acc0));
        yp[(l + 1) * DD] = f2bf(fmaf(u1, Dd, acc1));
    }
}

// ---------------- K3: output projection via bf16 MFMA (no LDS) ----------------
// Out(16384,256) = Y @ W^T.  Block 128x128, 4 waves 2x2, wave tile 64x64.
__global__ __launch_bounds__(256) void k3_mfma(
    const unsigned short* __restrict__ Ybf,   // (16384,256)
    const unsigned short* __restrict__ Wbf,   // (256,256)
    float* __restrict__ Out)
{
    int wave = threadIdx.x >> 6;
    int lane = threadIdx.x & 63;
    int row0 = (blockIdx.x >> 1) * 128 + (wave >> 1) * 64;
    int col0 = (blockIdx.x & 1) * 128 + (wave & 1) * 64;
    int rl = lane & 15, kb = lane >> 4;

    f32x4 acc[4][4] = {};
    bf16x8 af[4], bf[4], afn[4], bfn[4];

    #pragma unroll
    for (int i = 0; i < 4; ++i)
        af[i] = *reinterpret_cast<const bf16x8*>(&Ybf[(size_t)(row0 + i * 16 + rl) * DD + kb * 8]);
    #pragma unroll
    for (int j = 0; j < 4; ++j)
        bf[j] = *reinterpret_cast<const bf16x8*>(&Wbf[(size_t)(col0 + j * 16 + rl) * DD + kb * 8]);

    #pragma unroll
    for (int ks = 0; ks < 8; ++ks) {
        int kn = (ks + 1) * 32 + kb * 8;
        if (ks < 7) {
            #pragma unroll
            for (int i = 0; i < 4; ++i)
                afn[i] = *reinterpret_cast<const bf16x8*>(&Ybf[(size_t)(row0 + i * 16 + rl) * DD + kn]);
            #pragma unroll
            for (int j = 0; j < 4; ++j)
                bfn[j] = *reinterpret_cast<const bf16x8*>(&Wbf[(size_t)(col0 + j * 16 + rl) * DD + kn]);
        }
        #pragma unroll
        for (int i = 0; i < 4; ++i)
            #pragma unroll
            for (int j = 0; j < 4; ++j)
                acc[i][j] = __builtin_amdgcn_mfma_f32_16x16x32_bf16(af[i], bf[j], acc[i][j], 0, 0, 0);
        #pragma unroll
        for (int i = 0; i < 4; ++i) { af[i] = afn[i]; bf[i] = bfn[i]; }
    }

    // C/D: col = lane&15, row = (lane>>4)*4 + reg
    #pragma unroll
    for (int i = 0; i < 4; ++i)
        #pragma unroll
        for (int j = 0; j < 4; ++j)
            #pragma unroll
            for (int reg = 0; reg < 4; ++reg)
                Out[(size_t)(row0 + i * 16 + kb * 4 + reg) * DD + col0 + j * 16 + rl] = acc[i][j][reg];
}

extern "C" void kernel_launch(void* const* d_in, const int* in_sizes, int n_in,
                              void* d_out, int out_size, void* d_ws, size_t ws_size,
                              hipStream_t stream) {
    const float* pos  = (const float*)d_in[0];   // (L,B,D)
    const float* flow = (const float*)d_in[1];   // (L,B,D)
    const float* h0   = (const float*)d_in[2];   // (B,D,NS)
    const float* xw   = (const float*)d_in[3];   // (48,D)
    const float* dtw  = (const float*)d_in[4];   // (D,16)
    const float* dtb  = (const float*)d_in[5];   // (D)
    const float* alog = (const float*)d_in[6];   // (D,NS)
    const float* dpar = (const float*)d_in[7];   // (D)
    const float* ow   = (const float*)d_in[8];   // (256,256)

    float* out = (float*)d_out;                  // out0: 4,194,304 then h_final: 131,072

    float* ws    = (float*)d_ws;
    float* delta = ws;                           // 4,194,304 floats
    float* Bmw   = ws + 4194304;                 //   262,144
    float* Cmw   = ws + 4456448;                 //   262,144
    float* aprod = ws + 4718592;                 // 2,097,152 (reused as ybf after scanB)
    float* hpart = ws + 6815744;                 // 2,097,152
    unsigned short* ybf = (unsigned short*)aprod;            // 16384*256 bf16 = 8 MB
    unsigned short* wbf = (unsigned short*)(ws + 8912896);   // 65536 bf16 = 128 KB
    // total ws usage: 8,945,664 floats = 35.8 MB

    float* h_out = out + 32 * 512 * 256;

    k0_wbf  <<<64,   256, 0, stream>>>(ow, wbf);
    k1_proj <<<512,  256, 0, stream>>>(flow, xw, dtw, dtb, delta, Bmw, Cmw);
    k2_scanA<<<512,  256, 0, stream>>>(pos, alog, delta, Bmw, aprod, hpart);
    k2_scanB<<<512,  256, 0, stream>>>(h0, aprod, hpart, h_out);
    k2_scanC<<<512,  256, 0, stream>>>(pos, alog, dpar, delta, Bmw, Cmw, hpart, ybf);
    k3_mfma <<<256,  256, 0, stream>>>(ybf, wbf, out);
}

// Round 5
// 191.141 us; speedup vs baseline: 1.3583x; 1.3583x over previous
//
#include <hip/hip_runtime.h>
#include <hip/hip_bf16.h>

#define LL 512
#define BB 32
#define DD 256
#define NS 16
#define RK 16
#define CH 16          // chunks over L
#define LC 32          // L per chunk

typedef __attribute__((ext_vector_type(8))) short bf16x8;
typedef __attribute__((ext_vector_type(4))) float f32x4;

// load 16 consecutive floats into a scalar array (float4 x4)
#define LD16(dst, src, off) { \
  float4 _v0 = *reinterpret_cast<const float4*>(&(src)[(off)]); \
  float4 _v1 = *reinterpret_cast<const float4*>(&(src)[(off)+4]); \
  float4 _v2 = *reinterpret_cast<const float4*>(&(src)[(off)+8]); \
  float4 _v3 = *reinterpret_cast<const float4*>(&(src)[(off)+12]); \
  dst[0]=_v0.x; dst[1]=_v0.y; dst[2]=_v0.z; dst[3]=_v0.w; \
  dst[4]=_v1.x; dst[5]=_v1.y; dst[6]=_v1.z; dst[7]=_v1.w; \
  dst[8]=_v2.x; dst[9]=_v2.y; dst[10]=_v2.z; dst[11]=_v2.w; \
  dst[12]=_v3.x; dst[13]=_v3.y; dst[14]=_v3.z; dst[15]=_v3.w; }

#define CP16(dst, src) { _Pragma("unroll") for (int _i = 0; _i < 16; ++_i) dst[_i] = src[_i]; }

static __device__ __forceinline__ unsigned short f2bf(float x) {
    __hip_bfloat16 h = __float2bfloat16(x);
    return *reinterpret_cast<unsigned short*>(&h);
}

// ---------------- K0: W -> bf16 ----------------
__global__ __launch_bounds__(256) void k0_wbf(
    const float* __restrict__ W, unsigned short* __restrict__ Wbf)
{
    int i = (blockIdx.x * 256 + threadIdx.x) * 4;
    float4 v = *reinterpret_cast<const float4*>(&W[i]);
    ushort4 o;
    o.x = f2bf(v.x); o.y = f2bf(v.y); o.z = f2bf(v.z); o.w = f2bf(v.w);
    *reinterpret_cast<ushort4*>(&Wbf[i]) = o;
}

// ---------------- K1: projections ----------------
// block: 32 rows.  W staged in LDS in two 24-row halves (fp32).
// stage1: thread (r = tid>>3, cg = tid&7) computes, per half h,
//   x_dbl[r][24h + cg*3 .. +2].  sflow: 8-lane broadcast, banks 4r -> conflict-free.
//   sW: c = 3cg+j, banks (12cg+4j+k)%32 spacing 4 -> conflict-free broadcast.
// stage2: thread d computes delta for 32 rows (sdbl reads wave-uniform broadcast).
__global__ __launch_bounds__(256) void k1_proj(
    const float* __restrict__ flow,       // (L,B,D)
    const float* __restrict__ x_proj_w,   // (48,D)
    const float* __restrict__ dt_w,       // (D,RK)
    const float* __restrict__ dt_b,       // (D)
    float* __restrict__ delta,            // (B,L,D)
    float* __restrict__ Bm,               // (B,L,NS)
    float* __restrict__ Cm)               // (B,L,NS)
{
    const int ROWS = 32;
    const int FP = 260;                   // sflow row stride; 260%32==4
    const int SP = 49;                    // sdbl row stride
    __shared__ float sW[24 * FP];         // 24.96 KB (one half of x_proj_w)
    __shared__ float sflow[ROWS * FP];    // 33.3 KB
    __shared__ float sdbl[ROWS * SP];     // 6.3 KB    (total 64,512 B)
    int tid = threadIdx.x;
    int row0 = blockIdx.x * ROWS;         // row = b*512 + l

    // stage flow rows: 32 rows x 64 float4 = 2048 slots
    #pragma unroll
    for (int jj = 0; jj < 8; ++jj) {
        int s = tid + jj * 256;
        int r = s >> 6, c4 = s & 63;
        int row = row0 + r;
        int b = row >> 9, l = row & 511;
        float4 v = *reinterpret_cast<const float4*>(&flow[(l * BB + b) * DD + c4 * 4]);
        *reinterpret_cast<float4*>(&sflow[r * FP + c4 * 4]) = v;
    }

    int r = tid >> 3, cg = tid & 7;
    const float* frow = &sflow[r * FP];

    for (int half = 0; half < 2; ++half) {
        if (half) __syncthreads();        // all reads of sW half0 done
        // stage 24 W rows: 24*64 = 1536 float4 slots
        #pragma unroll
        for (int jj = 0; jj < 6; ++jj) {
            int s = tid + jj * 256;
            int c = s >> 6, c4 = s & 63;
            float4 v = *reinterpret_cast<const float4*>(&x_proj_w[(half * 24 + c) * DD + c4 * 4]);
            *reinterpret_cast<float4*>(&sW[c * FP + c4 * 4]) = v;
        }
        __syncthreads();                  // sW ready (and sflow on half 0)

        float acc3[3] = {};
        const float* w0 = &sW[(cg * 3 + 0) * FP];
        const float* w1 = &sW[(cg * 3 + 1) * FP];
        const float* w2 = &sW[(cg * 3 + 2) * FP];
        for (int k = 0; k < DD; k += 4) {
            float4 fv = *reinterpret_cast<const float4*>(&frow[k]);
            float4 wv0 = *reinterpret_cast<const float4*>(&w0[k]);
            float4 wv1 = *reinterpret_cast<const float4*>(&w1[k]);
            float4 wv2 = *reinterpret_cast<const float4*>(&w2[k]);
            acc3[0] = fmaf(fv.x, wv0.x, acc3[0]); acc3[0] = fmaf(fv.y, wv0.y, acc3[0]);
            acc3[0] = fmaf(fv.z, wv0.z, acc3[0]); acc3[0] = fmaf(fv.w, wv0.w, acc3[0]);
            acc3[1] = fmaf(fv.x, wv1.x, acc3[1]); acc3[1] = fmaf(fv.y, wv1.y, acc3[1]);
            acc3[1] = fmaf(fv.z, wv1.z, acc3[1]); acc3[1] = fmaf(fv.w, wv1.w, acc3[1]);
            acc3[2] = fmaf(fv.x, wv2.x, acc3[2]); acc3[2] = fmaf(fv.y, wv2.y, acc3[2]);
            acc3[2] = fmaf(fv.z, wv2.z, acc3[2]); acc3[2] = fmaf(fv.w, wv2.w, acc3[2]);
        }
        #pragma unroll
        for (int j = 0; j < 3; ++j) sdbl[r * SP + half * 24 + cg * 3 + j] = acc3[j];
    }
    __syncthreads();

    // B/C copy out (coalesced)
    #pragma unroll
    for (int jj = 0; jj < 2; ++jj) {
        int idx = tid + jj * 256;         // 512 elems
        int rr = idx >> 4, c = idx & 15;
        Bm[(row0 + rr) * NS + c] = sdbl[rr * SP + RK + c];
        Cm[(row0 + rr) * NS + c] = sdbl[rr * SP + RK + NS + c];
    }

    // stage 2: delta = softplus(dr @ dtw.T + b), thread d = tid
    float wreg[RK];
    #pragma unroll
    for (int k = 0; k < RK; k += 4) {
        float4 v = *reinterpret_cast<const float4*>(&dt_w[tid * RK + k]);
        wreg[k] = v.x; wreg[k + 1] = v.y; wreg[k + 2] = v.z; wreg[k + 3] = v.w;
    }
    float bias = dt_b[tid];
    for (int rr = 0; rr < ROWS; ++rr) {
        const float* srow = &sdbl[rr * SP];
        float s = bias;
        #pragma unroll
        for (int k = 0; k < RK; ++k) s = fmaf(srow[k], wreg[k], s);
        float sp = fmaxf(s, 0.f) + log1pf(__expf(-fabsf(s)));
        delta[(size_t)(row0 + rr) * DD + tid] = sp;
    }
}

// ---------------- K2 pass A: per-chunk local scan (pipelined) ----------------
__global__ __launch_bounds__(256) void k2_scanA(
    const float* __restrict__ u_pos,    // (L,B,D)
    const float* __restrict__ A_log,    // (D,NS)
    const float* __restrict__ delta,    // (B,L,D)
    const float* __restrict__ Bm,       // (B,L,NS)
    float* __restrict__ aprod,          // (B,CH,D,NS)
    float* __restrict__ hpart)          // (B,CH,D,NS)
{
    int b = blockIdx.x >> 4;
    int c = blockIdx.x & 15;
    int d = threadIdx.x;
    int l0 = c * LC;

    float a[NS];
    #pragma unroll
    for (int n = 0; n < NS; n += 4) {
        float4 v = *reinterpret_cast<const float4*>(&A_log[d * NS + n]);
        a[n]     = -__expf(v.x) * 1.44269504f;   // dA = exp2(dlt*a)
        a[n + 1] = -__expf(v.y) * 1.44269504f;
        a[n + 2] = -__expf(v.z) * 1.44269504f;
        a[n + 3] = -__expf(v.w) * 1.44269504f;
    }
    float h[NS], ap[NS];
    #pragma unroll
    for (int n = 0; n < NS; ++n) { h[n] = 0.f; ap[n] = 1.f; }

    const float* dp = delta + ((size_t)b * LL + l0) * DD + d;
    const float* up = u_pos + ((size_t)l0 * BB + b) * DD + d;
    const float* Bp = Bm + ((size_t)b * LL + l0) * NS;

    // prologue: pair 0
    float d0 = dp[0], d1 = dp[DD];
    float u0 = up[0], u1 = up[BB * DD];
    float B0[NS], B1[NS];
    LD16(B0, Bp, 0);
    LD16(B1, Bp, NS);

    for (int l = 0; l < LC; l += 2) {
        // prefetch pair l+2 (clamped)
        int lp = (l + 2 < LC) ? l + 2 : l;
        float d0n = dp[lp * DD],      d1n = dp[(lp + 1) * DD];
        float u0n = up[lp * BB * DD], u1n = up[(lp + 1) * BB * DD];
        float B0n[NS], B1n[NS];
        LD16(B0n, Bp, lp * NS);
        LD16(B1n, Bp, (lp + 1) * NS);

        float du0 = d0 * u0, du1 = d1 * u1;
        #pragma unroll
        for (int n = 0; n < NS; ++n) {
            float dA = exp2f(d0 * a[n]);
            ap[n] *= dA;
            h[n] = fmaf(dA, h[n], du0 * B0[n]);
        }
        #pragma unroll
        for (int n = 0; n < NS; ++n) {
            float dA = exp2f(d1 * a[n]);
            ap[n] *= dA;
            h[n] = fmaf(dA, h[n], du1 * B1[n]);
        }
        d0 = d0n; d1 = d1n; u0 = u0n; u1 = u1n;
        CP16(B0, B0n); CP16(B1, B1n);
    }

    size_t o = (((size_t)b * CH + c) * DD + d) * NS;
    #pragma unroll
    for (int n = 0; n < NS; n += 4) {
        *reinterpret_cast<float4*>(&aprod[o + n]) = make_float4(ap[n], ap[n+1], ap[n+2], ap[n+3]);
        *reinterpret_cast<float4*>(&hpart[o + n]) = make_float4(h[n], h[n+1], h[n+2], h[n+3]);
    }
}

// ---------------- K2 pass B: combine chunks ----------------
__global__ __launch_bounds__(256) void k2_scanB(
    const float* __restrict__ h0,       // (B,D,NS)
    const float* __restrict__ aprod,
    float* __restrict__ hpart,          // in: local results; out: h_in per chunk
    float* __restrict__ h_out)          // (B,D,NS)
{
    int t = blockIdx.x * 256 + threadIdx.x;
    float s = h0[t];
    int b = t >> 12, dn = t & 4095;
    for (int c = 0; c < CH; ++c) {
        size_t idx = ((size_t)(b * CH + c) << 12) + dn;
        float apv = aprod[idx];
        float hpv = hpart[idx];
        hpart[idx] = s;
        s = fmaf(apv, s, hpv);
    }
    h_out[t] = s;
}

// ---------------- K2 pass C: re-scan with true h_in, emit y (bf16, pipelined) ----------------
__global__ __launch_bounds__(256) void k2_scanC(
    const float* __restrict__ u_pos,
    const float* __restrict__ A_log,
    const float* __restrict__ Dp,
    const float* __restrict__ delta,
    const float* __restrict__ Bm,
    const float* __restrict__ Cm,
    const float* __restrict__ hpart,    // h_in per chunk
    unsigned short* __restrict__ ybf)   // (B,L,D) bf16
{
    int b = blockIdx.x >> 4;
    int c = blockIdx.x & 15;
    int d = threadIdx.x;
    int l0 = c * LC;

    float a[NS];
    #pragma unroll
    for (int n = 0; n < NS; n += 4) {
        float4 v = *reinterpret_cast<const float4*>(&A_log[d * NS + n]);
        a[n]     = -__expf(v.x) * 1.44269504f;
        a[n + 1] = -__expf(v.y) * 1.44269504f;
        a[n + 2] = -__expf(v.z) * 1.44269504f;
        a[n + 3] = -__expf(v.w) * 1.44269504f;
    }
    float h[NS];
    {
        size_t o = (((size_t)b * CH + c) * DD + d) * NS;
        LD16(h, hpart, o);
    }
    float Dd = Dp[d];

    const float* dp = delta + ((size_t)b * LL + l0) * DD + d;
    const float* up = u_pos + ((size_t)l0 * BB + b) * DD + d;
    const float* Bp = Bm + ((size_t)b * LL + l0) * NS;
    const float* Cp = Cm + ((size_t)b * LL + l0) * NS;
    unsigned short* yp = ybf + ((size_t)b * LL + l0) * DD + d;

    // prologue: pair 0
    float d0 = dp[0], d1 = dp[DD];
    float u0 = up[0], u1 = up[BB * DD];
    float B0[NS], B1[NS], C0[NS], C1[NS];
    LD16(B0, Bp, 0);
    LD16(B1, Bp, NS);
    LD16(C0, Cp, 0);
    LD16(C1, Cp, NS);

    for (int l = 0; l < LC; l += 2) {
        int lp = (l + 2 < LC) ? l + 2 : l;
        float d0n = dp[lp * DD],      d1n = dp[(lp + 1) * DD];
        float u0n = up[lp * BB * DD], u1n = up[(lp + 1) * BB * DD];
        float B0n[NS], B1n[NS], C0n[NS], C1n[NS];
        LD16(B0n, Bp, lp * NS);
        LD16(B1n, Bp, (lp + 1) * NS);
        LD16(C0n, Cp, lp * NS);
        LD16(C1n, Cp, (lp + 1) * NS);

        float du0 = d0 * u0, du1 = d1 * u1;
        float acc0 = 0.f, acc1 = 0.f;
        #pragma unroll
        for (int n = 0; n < NS; ++n) {
            float dA = exp2f(d0 * a[n]);
            h[n] = fmaf(dA, h[n], du0 * B0[n]);
            acc0 = fmaf(h[n], C0[n], acc0);
        }
        #pragma unroll
        for (int n = 0; n < NS; ++n) {
            float dA = exp2f(d1 * a[n]);
            h[n] = fmaf(dA, h[n], du1 * B1[n]);
            acc1 = fmaf(h[n], C1[n], acc1);
        }
        yp[l * DD]       = f2bf(fmaf(u0, Dd, acc0));
        yp[(l + 1) * DD] = f2bf(fmaf(u1, Dd, acc1));

        d0 = d0n; d1 = d1n; u0 = u0n; u1 = u1n;
        CP16(B0, B0n); CP16(B1, B1n); CP16(C0, C0n); CP16(C1, C1n);
    }
}

// ---------------- K3: output projection via bf16 MFMA (no LDS) ----------------
// Out(16384,256) = Y @ W^T.  Block 128x128, 4 waves 2x2, wave tile 64x64.
__global__ __launch_bounds__(256) void k3_mfma(
    const unsigned short* __restrict__ Ybf,   // (16384,256)
    const unsigned short* __restrict__ Wbf,   // (256,256)
    float* __restrict__ Out)
{
    int wave = threadIdx.x >> 6;
    int lane = threadIdx.x & 63;
    int row0 = (blockIdx.x >> 1) * 128 + (wave >> 1) * 64;
    int col0 = (blockIdx.x & 1) * 128 + (wave & 1) * 64;
    int rl = lane & 15, kb = lane >> 4;

    f32x4 acc[4][4] = {};
    bf16x8 af[4], bf[4], afn[4], bfn[4];

    #pragma unroll
    for (int i = 0; i < 4; ++i)
        af[i] = *reinterpret_cast<const bf16x8*>(&Ybf[(size_t)(row0 + i * 16 + rl) * DD + kb * 8]);
    #pragma unroll
    for (int j = 0; j < 4; ++j)
        bf[j] = *reinterpret_cast<const bf16x8*>(&Wbf[(size_t)(col0 + j * 16 + rl) * DD + kb * 8]);

    #pragma unroll
    for (int ks = 0; ks < 8; ++ks) {
        int kn = (ks + 1) * 32 + kb * 8;
        if (ks < 7) {
            #pragma unroll
            for (int i = 0; i < 4; ++i)
                afn[i] = *reinterpret_cast<const bf16x8*>(&Ybf[(size_t)(row0 + i * 16 + rl) * DD + kn]);
            #pragma unroll
            for (int j = 0; j < 4; ++j)
                bfn[j] = *reinterpret_cast<const bf16x8*>(&Wbf[(size_t)(col0 + j * 16 + rl) * DD + kn]);
        }
        #pragma unroll
        for (int i = 0; i < 4; ++i)
            #pragma unroll
            for (int j = 0; j < 4; ++j)
                acc[i][j] = __builtin_amdgcn_mfma_f32_16x16x32_bf16(af[i], bf[j], acc[i][j], 0, 0, 0);
        #pragma unroll
        for (int i = 0; i < 4; ++i) { af[i] = afn[i]; bf[i] = bfn[i]; }
    }

    // C/D: col = lane&15, row = (lane>>4)*4 + reg
    #pragma unroll
    for (int i = 0; i < 4; ++i)
        #pragma unroll
        for (int j = 0; j < 4; ++j)
            #pragma unroll
            for (int reg = 0; reg < 4; ++reg)
                Out[(size_t)(row0 + i * 16 + kb * 4 + reg) * DD + col0 + j * 16 + rl] = acc[i][j][reg];
}

extern "C" void kernel_launch(void* const* d_in, const int* in_sizes, int n_in,
                              void* d_out, int out_size, void* d_ws, size_t ws_size,
                              hipStream_t stream) {
    const float* pos  = (const float*)d_in[0];   // (L,B,D)
    const float* flow = (const float*)d_in[1];   // (L,B,D)
    const float* h0   = (const float*)d_in[2];   // (B,D,NS)
    const float* xw   = (const float*)d_in[3];   // (48,D)
    const float* dtw  = (const float*)d_in[4];   // (D,16)
    const float* dtb  = (const float*)d_in[5];   // (D)
    const float* alog = (const float*)d_in[6];   // (D,NS)
    const float* dpar = (const float*)d_in[7];   // (D)
    const float* ow   = (const float*)d_in[8];   // (256,256)

    float* out = (float*)d_out;                  // out0: 4,194,304 then h_final: 131,072

    float* ws    = (float*)d_ws;
    float* delta = ws;                           // 4,194,304 floats
    float* Bmw   = ws + 4194304;                 //   262,144
    float* Cmw   = ws + 4456448;                 //   262,144
    float* aprod = ws + 4718592;                 // 2,097,152 (reused as ybf after scanB)
    float* hpart = ws + 6815744;                 // 2,097,152
    unsigned short* ybf = (unsigned short*)aprod;            // 16384*256 bf16 = 8 MB
    unsigned short* wbf = (unsigned short*)(ws + 8912896);   // 65536 bf16 = 128 KB
    // total ws usage: 8,945,664 floats = 35.8 MB

    float* h_out = out + 32 * 512 * 256;

    k0_wbf  <<<64,   256, 0, stream>>>(ow, wbf);
    k1_proj <<<512,  256, 0, stream>>>(flow, xw, dtw, dtb, delta, Bmw, Cmw);
    k2_scanA<<<512,  256, 0, stream>>>(pos, alog, delta, Bmw, aprod, hpart);
    k2_scanB<<<512,  256, 0, stream>>>(h0, aprod, hpart, h_out);
    k2_scanC<<<512,  256, 0, stream>>>(pos, alog, dpar, delta, Bmw, Cmw, hpart, ybf);
    k3_mfma <<<256,  256, 0, stream>>>(ybf, wbf, out);
}

// Round 6
// 189.422 us; speedup vs baseline: 1.3706x; 1.0091x over previous
//
#include <hip/hip_runtime.h>
#include <hip/hip_bf16.h>

#define LL 512
#define BB 32
#define DD 256
#define NS 16
#define RK 16
#define CH2 32         // chunks over L (fused scan)
#define LC2 16         // L per chunk
#define DT 8           // d-channels per block tile

typedef __attribute__((ext_vector_type(8))) short bf16x8;
typedef __attribute__((ext_vector_type(4))) float f32x4;

// load 16 consecutive floats into a scalar array (float4 x4)
#define LD16(dst, src, off) { \
  float4 _v0 = *reinterpret_cast<const float4*>(&(src)[(off)]); \
  float4 _v1 = *reinterpret_cast<const float4*>(&(src)[(off)+4]); \
  float4 _v2 = *reinterpret_cast<const float4*>(&(src)[(off)+8]); \
  float4 _v3 = *reinterpret_cast<const float4*>(&(src)[(off)+12]); \
  dst[0]=_v0.x; dst[1]=_v0.y; dst[2]=_v0.z; dst[3]=_v0.w; \
  dst[4]=_v1.x; dst[5]=_v1.y; dst[6]=_v1.z; dst[7]=_v1.w; \
  dst[8]=_v2.x; dst[9]=_v2.y; dst[10]=_v2.z; dst[11]=_v2.w; \
  dst[12]=_v3.x; dst[13]=_v3.y; dst[14]=_v3.z; dst[15]=_v3.w; }

static __device__ __forceinline__ unsigned short f2bf(float x) {
    __hip_bfloat16 h = __float2bfloat16(x);
    return *reinterpret_cast<unsigned short*>(&h);
}

// ---------------- K0: W -> bf16 ----------------
__global__ __launch_bounds__(256) void k0_wbf(
    const float* __restrict__ W, unsigned short* __restrict__ Wbf)
{
    int i = (blockIdx.x * 256 + threadIdx.x) * 4;
    float4 v = *reinterpret_cast<const float4*>(&W[i]);
    ushort4 o;
    o.x = f2bf(v.x); o.y = f2bf(v.y); o.z = f2bf(v.z); o.w = f2bf(v.w);
    *reinterpret_cast<ushort4*>(&Wbf[i]) = o;
}

// ---------------- K1: projections (unchanged from R5 — passed) ----------------
__global__ __launch_bounds__(256) void k1_proj(
    const float* __restrict__ flow,       // (L,B,D)
    const float* __restrict__ x_proj_w,   // (48,D)
    const float* __restrict__ dt_w,       // (D,RK)
    const float* __restrict__ dt_b,       // (D)
    float* __restrict__ delta,            // (B,L,D)
    float* __restrict__ Bm,               // (B,L,NS)
    float* __restrict__ Cm)               // (B,L,NS)
{
    const int ROWS = 32;
    const int FP = 260;                   // row stride; 260%32==4
    const int SP = 49;
    __shared__ float sW[24 * FP];
    __shared__ float sflow[ROWS * FP];
    __shared__ float sdbl[ROWS * SP];
    int tid = threadIdx.x;
    int row0 = blockIdx.x * ROWS;         // row = b*512 + l

    #pragma unroll
    for (int jj = 0; jj < 8; ++jj) {
        int s = tid + jj * 256;
        int r = s >> 6, c4 = s & 63;
        int row = row0 + r;
        int b = row >> 9, l = row & 511;
        float4 v = *reinterpret_cast<const float4*>(&flow[(l * BB + b) * DD + c4 * 4]);
        *reinterpret_cast<float4*>(&sflow[r * FP + c4 * 4]) = v;
    }

    int r = tid >> 3, cg = tid & 7;
    const float* frow = &sflow[r * FP];

    for (int half = 0; half < 2; ++half) {
        if (half) __syncthreads();
        #pragma unroll
        for (int jj = 0; jj < 6; ++jj) {
            int s = tid + jj * 256;
            int c = s >> 6, c4 = s & 63;
            float4 v = *reinterpret_cast<const float4*>(&x_proj_w[(half * 24 + c) * DD + c4 * 4]);
            *reinterpret_cast<float4*>(&sW[c * FP + c4 * 4]) = v;
        }
        __syncthreads();

        float acc3[3] = {};
        const float* w0 = &sW[(cg * 3 + 0) * FP];
        const float* w1 = &sW[(cg * 3 + 1) * FP];
        const float* w2 = &sW[(cg * 3 + 2) * FP];
        for (int k = 0; k < DD; k += 4) {
            float4 fv = *reinterpret_cast<const float4*>(&frow[k]);
            float4 wv0 = *reinterpret_cast<const float4*>(&w0[k]);
            float4 wv1 = *reinterpret_cast<const float4*>(&w1[k]);
            float4 wv2 = *reinterpret_cast<const float4*>(&w2[k]);
            acc3[0] = fmaf(fv.x, wv0.x, acc3[0]); acc3[0] = fmaf(fv.y, wv0.y, acc3[0]);
            acc3[0] = fmaf(fv.z, wv0.z, acc3[0]); acc3[0] = fmaf(fv.w, wv0.w, acc3[0]);
            acc3[1] = fmaf(fv.x, wv1.x, acc3[1]); acc3[1] = fmaf(fv.y, wv1.y, acc3[1]);
            acc3[1] = fmaf(fv.z, wv1.z, acc3[1]); acc3[1] = fmaf(fv.w, wv1.w, acc3[1]);
            acc3[2] = fmaf(fv.x, wv2.x, acc3[2]); acc3[2] = fmaf(fv.y, wv2.y, acc3[2]);
            acc3[2] = fmaf(fv.z, wv2.z, acc3[2]); acc3[2] = fmaf(fv.w, wv2.w, acc3[2]);
        }
        #pragma unroll
        for (int j = 0; j < 3; ++j) sdbl[r * SP + half * 24 + cg * 3 + j] = acc3[j];
    }
    __syncthreads();

    #pragma unroll
    for (int jj = 0; jj < 2; ++jj) {
        int idx = tid + jj * 256;
        int rr = idx >> 4, c = idx & 15;
        Bm[(row0 + rr) * NS + c] = sdbl[rr * SP + RK + c];
        Cm[(row0 + rr) * NS + c] = sdbl[rr * SP + RK + NS + c];
    }

    float wreg[RK];
    #pragma unroll
    for (int k = 0; k < RK; k += 4) {
        float4 v = *reinterpret_cast<const float4*>(&dt_w[tid * RK + k]);
        wreg[k] = v.x; wreg[k + 1] = v.y; wreg[k + 2] = v.z; wreg[k + 3] = v.w;
    }
    float bias = dt_b[tid];
    for (int rr = 0; rr < ROWS; ++rr) {
        const float* srow = &sdbl[rr * SP];
        float s = bias;
        #pragma unroll
        for (int k = 0; k < RK; ++k) s = fmaf(srow[k], wreg[k], s);
        float sp = fmaxf(s, 0.f) + log1pf(__expf(-fabsf(s)));
        delta[(size_t)(row0 + rr) * DD + tid] = sp;
    }
}

// ---------------- K2 fused: chunk scan -> LDS prefix -> re-scan ----------------
// grid: b (32) x d-tile (32);  block 256 = chunk c (32) x channel dl (8)
__global__ __launch_bounds__(256) void k2_fused(
    const float* __restrict__ u_pos,    // (L,B,D)
    const float* __restrict__ h0,       // (B,D,NS)
    const float* __restrict__ A_log,    // (D,NS)
    const float* __restrict__ Dp,       // (D)
    const float* __restrict__ delta,    // (B,L,D)
    const float* __restrict__ Bm,       // (B,L,NS)
    const float* __restrict__ Cm,       // (B,L,NS)
    unsigned short* __restrict__ ybf,   // (B,L,D) bf16
    float* __restrict__ h_out)          // (B,D,NS)
{
    __shared__ float lap[NS * CH2 * DT];   // 16KB  [n][c][dl]; reused as h_in after phase B
    __shared__ float lhp[NS * CH2 * DT];   // 16KB

    int tid = threadIdx.x;
    int b  = blockIdx.x >> 5;
    int dt = blockIdx.x & 31;
    int dl = tid & 7, c = tid >> 3;        // dl 0..7, c 0..31
    int d  = dt * DT + dl;
    int l0 = c * LC2;

    // per-thread A coefficients (folded log2e)
    float a[NS];
    #pragma unroll
    for (int n = 0; n < NS; n += 4) {
        float4 v = *reinterpret_cast<const float4*>(&A_log[d * NS + n]);
        a[n]     = -__expf(v.x) * 1.44269504f;
        a[n + 1] = -__expf(v.y) * 1.44269504f;
        a[n + 2] = -__expf(v.z) * 1.44269504f;
        a[n + 3] = -__expf(v.w) * 1.44269504f;
    }

    const float* dp = delta + ((size_t)b * LL + l0) * DD + d;
    const float* up = u_pos + ((size_t)l0 * BB + b) * DD + d;
    const float* Bp = Bm + ((size_t)b * LL + l0) * NS;
    const float* Cp = Cm + ((size_t)b * LL + l0) * NS;

    // ---- phase A: local chunk scan from zero ----
    float h[NS], ap[NS];
    #pragma unroll
    for (int n = 0; n < NS; ++n) { h[n] = 0.f; ap[n] = 1.f; }

    for (int l = 0; l < LC2; l += 2) {
        float d0 = dp[l * DD],        d1 = dp[(l + 1) * DD];
        float u0 = up[l * BB * DD],   u1 = up[(l + 1) * BB * DD];
        float B0[NS], B1[NS];
        LD16(B0, Bp, l * NS);
        LD16(B1, Bp, (l + 1) * NS);
        float du0 = d0 * u0, du1 = d1 * u1;
        #pragma unroll
        for (int n = 0; n < NS; ++n) {
            float dA = exp2f(d0 * a[n]);
            ap[n] *= dA;
            h[n] = fmaf(dA, h[n], du0 * B0[n]);
        }
        #pragma unroll
        for (int n = 0; n < NS; ++n) {
            float dA = exp2f(d1 * a[n]);
            ap[n] *= dA;
            h[n] = fmaf(dA, h[n], du1 * B1[n]);
        }
    }
    #pragma unroll
    for (int n = 0; n < NS; ++n) {
        lap[n * (CH2 * DT) + c * DT + dl] = ap[n];   // banks (c*8+dl)%32: 2-way, free
        lhp[n * (CH2 * DT) + c * DT + dl] = h[n];
    }
    __syncthreads();

    // ---- phase B: sequential prefix over chunks (128 threads: (dl2, n2)) ----
    if (tid < DT * NS) {
        int dl2 = tid & 7, n2 = tid >> 3;
        float s = h0[((size_t)b * DD + dt * DT + dl2) * NS + n2];
        #pragma unroll 4
        for (int c2 = 0; c2 < CH2; ++c2) {
            int idx = n2 * (CH2 * DT) + c2 * DT + dl2;
            float apv = lap[idx];
            float hpv = lhp[idx];
            lap[idx] = s;                  // in-place: becomes h_in for chunk c2
            s = fmaf(apv, s, hpv);
        }
        h_out[((size_t)b * DD + dt * DT + dl2) * NS + n2] = s;
    }
    __syncthreads();

    // ---- phase C: re-scan with true h_in, emit y ----
    #pragma unroll
    for (int n = 0; n < NS; ++n)
        h[n] = lap[n * (CH2 * DT) + c * DT + dl];
    float Dd = Dp[d];
    unsigned short* yp = ybf + ((size_t)b * LL + l0) * DD + d;

    for (int l = 0; l < LC2; l += 2) {
        float d0 = dp[l * DD],        d1 = dp[(l + 1) * DD];
        float u0 = up[l * BB * DD],   u1 = up[(l + 1) * BB * DD];
        float B0[NS], B1[NS], C0[NS], C1[NS];
        LD16(B0, Bp, l * NS);
        LD16(B1, Bp, (l + 1) * NS);
        LD16(C0, Cp, l * NS);
        LD16(C1, Cp, (l + 1) * NS);

        float du0 = d0 * u0, du1 = d1 * u1;
        float acc0 = 0.f, acc1 = 0.f;
        #pragma unroll
        for (int n = 0; n < NS; ++n) {
            float dA = exp2f(d0 * a[n]);
            h[n] = fmaf(dA, h[n], du0 * B0[n]);
            acc0 = fmaf(h[n], C0[n], acc0);
        }
        #pragma unroll
        for (int n = 0; n < NS; ++n) {
            float dA = exp2f(d1 * a[n]);
            h[n] = fmaf(dA, h[n], du1 * B1[n]);
            acc1 = fmaf(h[n], C1[n], acc1);
        }
        yp[l * DD]       = f2bf(fmaf(u0, Dd, acc0));
        yp[(l + 1) * DD] = f2bf(fmaf(u1, Dd, acc1));
    }
}

// ---------------- K3: output projection via bf16 MFMA ----------------
// Out(16384,256) = Y @ W^T.  Block 64x128 (grid 512 = 2/CU), wave 32x64.
__global__ __launch_bounds__(256) void k3_mfma(
    const unsigned short* __restrict__ Ybf,   // (16384,256)
    const unsigned short* __restrict__ Wbf,   // (256,256)
    float* __restrict__ Out)
{
    int wave = threadIdx.x >> 6;
    int lane = threadIdx.x & 63;
    int row0 = (blockIdx.x >> 1) * 64 + (wave >> 1) * 32;
    int col0 = (blockIdx.x & 1) * 128 + (wave & 1) * 64;
    int rl = lane & 15, kb = lane >> 4;

    f32x4 acc[2][4] = {};
    bf16x8 af[2], bf[4], afn[2], bfn[4];

    #pragma unroll
    for (int i = 0; i < 2; ++i)
        af[i] = *reinterpret_cast<const bf16x8*>(&Ybf[(size_t)(row0 + i * 16 + rl) * DD + kb * 8]);
    #pragma unroll
    for (int j = 0; j < 4; ++j)
        bf[j] = *reinterpret_cast<const bf16x8*>(&Wbf[(size_t)(col0 + j * 16 + rl) * DD + kb * 8]);

    #pragma unroll
    for (int ks = 0; ks < 8; ++ks) {
        int kn = (ks + 1) * 32 + kb * 8;
        if (ks < 7) {
            #pragma unroll
            for (int i = 0; i < 2; ++i)
                afn[i] = *reinterpret_cast<const bf16x8*>(&Ybf[(size_t)(row0 + i * 16 + rl) * DD + kn]);
            #pragma unroll
            for (int j = 0; j < 4; ++j)
                bfn[j] = *reinterpret_cast<const bf16x8*>(&Wbf[(size_t)(col0 + j * 16 + rl) * DD + kn]);
        }
        #pragma unroll
        for (int i = 0; i < 2; ++i)
            #pragma unroll
            for (int j = 0; j < 4; ++j)
                acc[i][j] = __builtin_amdgcn_mfma_f32_16x16x32_bf16(af[i], bf[j], acc[i][j], 0, 0, 0);
        #pragma unroll
        for (int i = 0; i < 2; ++i) af[i] = afn[i];
        #pragma unroll
        for (int j = 0; j < 4; ++j) bf[j] = bfn[j];
    }

    // C/D: col = lane&15, row = (lane>>4)*4 + reg
    #pragma unroll
    for (int i = 0; i < 2; ++i)
        #pragma unroll
        for (int j = 0; j < 4; ++j)
            #pragma unroll
            for (int reg = 0; reg < 4; ++reg)
                Out[(size_t)(row0 + i * 16 + kb * 4 + reg) * DD + col0 + j * 16 + rl] = acc[i][j][reg];
}

extern "C" void kernel_launch(void* const* d_in, const int* in_sizes, int n_in,
                              void* d_out, int out_size, void* d_ws, size_t ws_size,
                              hipStream_t stream) {
    const float* pos  = (const float*)d_in[0];   // (L,B,D)
    const float* flow = (const float*)d_in[1];   // (L,B,D)
    const float* h0   = (const float*)d_in[2];   // (B,D,NS)
    const float* xw   = (const float*)d_in[3];   // (48,D)
    const float* dtw  = (const float*)d_in[4];   // (D,16)
    const float* dtb  = (const float*)d_in[5];   // (D)
    const float* alog = (const float*)d_in[6];   // (D,NS)
    const float* dpar = (const float*)d_in[7];   // (D)
    const float* ow   = (const float*)d_in[8];   // (256,256)

    float* out = (float*)d_out;                  // out0: 4,194,304 then h_final: 131,072

    float* ws    = (float*)d_ws;
    float* delta = ws;                           // 4,194,304 floats
    float* Bmw   = ws + 4194304;                 //   262,144
    float* Cmw   = ws + 4456448;                 //   262,144
    unsigned short* ybf = (unsigned short*)(ws + 4718592);   // 16384*256 bf16 = 8 MB
    unsigned short* wbf = (unsigned short*)(ws + 6815744);   // 65536 bf16 = 128 KB
    // total ws usage: ~27.5 MB

    float* h_out = out + 32 * 512 * 256;

    k0_wbf  <<<64,   256, 0, stream>>>(ow, wbf);
    k1_proj <<<512,  256, 0, stream>>>(flow, xw, dtw, dtb, delta, Bmw, Cmw);
    k2_fused<<<1024, 256, 0, stream>>>(pos, h0, alog, dpar, delta, Bmw, Cmw, ybf, h_out);
    k3_mfma <<<512,  256, 0, stream>>>(ybf, wbf, out);
}

// Round 8
// 181.352 us; speedup vs baseline: 1.4316x; 1.0445x over previous
//
#include <hip/hip_runtime.h>
#include <hip/hip_bf16.h>

#define LL 512
#define BB 32
#define DD 256
#define NS 16
#define RK 16
#define CH3 16         // chunks over L (fused scan)
#define LC3 32         // L per chunk
#define DT3 32         // d-channels per block tile

typedef __attribute__((ext_vector_type(8))) short bf16x8;
typedef __attribute__((ext_vector_type(4))) float f32x4;

// load 16 consecutive floats into a scalar array (float4 x4)
#define LD16(dst, src, off) { \
  float4 _v0 = *reinterpret_cast<const float4*>(&(src)[(off)]); \
  float4 _v1 = *reinterpret_cast<const float4*>(&(src)[(off)+4]); \
  float4 _v2 = *reinterpret_cast<const float4*>(&(src)[(off)+8]); \
  float4 _v3 = *reinterpret_cast<const float4*>(&(src)[(off)+12]); \
  dst[0]=_v0.x; dst[1]=_v0.y; dst[2]=_v0.z; dst[3]=_v0.w; \
  dst[4]=_v1.x; dst[5]=_v1.y; dst[6]=_v1.z; dst[7]=_v1.w; \
  dst[8]=_v2.x; dst[9]=_v2.y; dst[10]=_v2.z; dst[11]=_v2.w; \
  dst[12]=_v3.x; dst[13]=_v3.y; dst[14]=_v3.z; dst[15]=_v3.w; }

static __device__ __forceinline__ unsigned short f2bf(float x) {
    __hip_bfloat16 h = __float2bfloat16(x);
    return *reinterpret_cast<unsigned short*>(&h);
}

// ---------------- K0: W -> bf16 ----------------
__global__ __launch_bounds__(256) void k0_wbf(
    const float* __restrict__ W, unsigned short* __restrict__ Wbf)
{
    int i = (blockIdx.x * 256 + threadIdx.x) * 4;
    float4 v = *reinterpret_cast<const float4*>(&W[i]);
    ushort4 o;
    o.x = f2bf(v.x); o.y = f2bf(v.y); o.z = f2bf(v.z); o.w = f2bf(v.w);
    *reinterpret_cast<ushort4*>(&Wbf[i]) = o;
}

// ---------------- K1: projections (unchanged — passed R5/R6) ----------------
__global__ __launch_bounds__(256) void k1_proj(
    const float* __restrict__ flow,       // (L,B,D)
    const float* __restrict__ x_proj_w,   // (48,D)
    const float* __restrict__ dt_w,       // (D,RK)
    const float* __restrict__ dt_b,       // (D)
    float* __restrict__ delta,            // (B,L,D)
    float* __restrict__ Bm,               // (B,L,NS)
    float* __restrict__ Cm)               // (B,L,NS)
{
    const int ROWS = 32;
    const int FP = 260;                   // row stride; 260%32==4
    const int SP = 49;
    __shared__ float sW[24 * FP];
    __shared__ float sflow[ROWS * FP];
    __shared__ float sdbl[ROWS * SP];
    int tid = threadIdx.x;
    int row0 = blockIdx.x * ROWS;         // row = b*512 + l

    #pragma unroll
    for (int jj = 0; jj < 8; ++jj) {
        int s = tid + jj * 256;
        int r = s >> 6, c4 = s & 63;
        int row = row0 + r;
        int b = row >> 9, l = row & 511;
        float4 v = *reinterpret_cast<const float4*>(&flow[(l * BB + b) * DD + c4 * 4]);
        *reinterpret_cast<float4*>(&sflow[r * FP + c4 * 4]) = v;
    }

    int r = tid >> 3, cg = tid & 7;
    const float* frow = &sflow[r * FP];

    for (int half = 0; half < 2; ++half) {
        if (half) __syncthreads();
        #pragma unroll
        for (int jj = 0; jj < 6; ++jj) {
            int s = tid + jj * 256;
            int c = s >> 6, c4 = s & 63;
            float4 v = *reinterpret_cast<const float4*>(&x_proj_w[(half * 24 + c) * DD + c4 * 4]);
            *reinterpret_cast<float4*>(&sW[c * FP + c4 * 4]) = v;
        }
        __syncthreads();

        float acc3[3] = {};
        const float* w0 = &sW[(cg * 3 + 0) * FP];
        const float* w1 = &sW[(cg * 3 + 1) * FP];
        const float* w2 = &sW[(cg * 3 + 2) * FP];
        for (int k = 0; k < DD; k += 4) {
            float4 fv = *reinterpret_cast<const float4*>(&frow[k]);
            float4 wv0 = *reinterpret_cast<const float4*>(&w0[k]);
            float4 wv1 = *reinterpret_cast<const float4*>(&w1[k]);
            float4 wv2 = *reinterpret_cast<const float4*>(&w2[k]);
            acc3[0] = fmaf(fv.x, wv0.x, acc3[0]); acc3[0] = fmaf(fv.y, wv0.y, acc3[0]);
            acc3[0] = fmaf(fv.z, wv0.z, acc3[0]); acc3[0] = fmaf(fv.w, wv0.w, acc3[0]);
            acc3[1] = fmaf(fv.x, wv1.x, acc3[1]); acc3[1] = fmaf(fv.y, wv1.y, acc3[1]);
            acc3[1] = fmaf(fv.z, wv1.z, acc3[1]); acc3[1] = fmaf(fv.w, wv1.w, acc3[1]);
            acc3[2] = fmaf(fv.x, wv2.x, acc3[2]); acc3[2] = fmaf(fv.y, wv2.y, acc3[2]);
            acc3[2] = fmaf(fv.z, wv2.z, acc3[2]); acc3[2] = fmaf(fv.w, wv2.w, acc3[2]);
        }
        #pragma unroll
        for (int j = 0; j < 3; ++j) sdbl[r * SP + half * 24 + cg * 3 + j] = acc3[j];
    }
    __syncthreads();

    #pragma unroll
    for (int jj = 0; jj < 2; ++jj) {
        int idx = tid + jj * 256;
        int rr = idx >> 4, c = idx & 15;
        Bm[(row0 + rr) * NS + c] = sdbl[rr * SP + RK + c];
        Cm[(row0 + rr) * NS + c] = sdbl[rr * SP + RK + NS + c];
    }

    float wreg[RK];
    #pragma unroll
    for (int k = 0; k < RK; k += 4) {
        float4 v = *reinterpret_cast<const float4*>(&dt_w[tid * RK + k]);
        wreg[k] = v.x; wreg[k + 1] = v.y; wreg[k + 2] = v.z; wreg[k + 3] = v.w;
    }
    float bias = dt_b[tid];
    for (int rr = 0; rr < ROWS; ++rr) {
        const float* srow = &sdbl[rr * SP];
        float s = bias;
        #pragma unroll
        for (int k = 0; k < RK; ++k) s = fmaf(srow[k], wreg[k], s);
        float sp = fmaxf(s, 0.f) + log1pf(__expf(-fabsf(s)));
        delta[(size_t)(row0 + rr) * DD + tid] = sp;
    }
}

// ---------------- K2 fused: chunk scan -> LDS prefix -> re-scan ----------------
// grid: b (32) x d-tile (8);  block 512 = chunk c (16) x channel dl (32)
// wave = 2 chunks x 32 consecutive channels -> 128B contiguous per segment.
__global__ __launch_bounds__(512) void k2_fused(
    const float* __restrict__ u_pos,    // (L,B,D)
    const float* __restrict__ h0,       // (B,D,NS)
    const float* __restrict__ A_log,    // (D,NS)
    const float* __restrict__ Dp,       // (D)
    const float* __restrict__ delta,    // (B,L,D)
    const float* __restrict__ Bm,       // (B,L,NS)
    const float* __restrict__ Cm,       // (B,L,NS)
    unsigned short* __restrict__ ybf,   // (B,L,D) bf16
    float* __restrict__ h_out)          // (B,D,NS)
{
    extern __shared__ float smem[];            // 65536 B
    float* lap = smem;                         // [NS][CH3*DT3] = 16 x 512
    float* lhp = smem + NS * CH3 * DT3;

    int tid = threadIdx.x;
    int b  = blockIdx.x >> 3;
    int dt = blockIdx.x & 7;
    int dl = tid & 31, c = tid >> 5;           // dl 0..31, c 0..15
    int d  = dt * DT3 + dl;
    int l0 = c * LC3;

    // per-thread A coefficients (folded log2e)
    float a[NS];
    #pragma unroll
    for (int n = 0; n < NS; n += 4) {
        float4 v = *reinterpret_cast<const float4*>(&A_log[d * NS + n]);
        a[n]     = -__expf(v.x) * 1.44269504f;
        a[n + 1] = -__expf(v.y) * 1.44269504f;
        a[n + 2] = -__expf(v.z) * 1.44269504f;
        a[n + 3] = -__expf(v.w) * 1.44269504f;
    }

    const float* dp = delta + ((size_t)b * LL + l0) * DD + d;
    const float* up = u_pos + ((size_t)l0 * BB + b) * DD + d;
    const float* Bp = Bm + ((size_t)b * LL + l0) * NS;
    const float* Cp = Cm + ((size_t)b * LL + l0) * NS;

    // ---- phase A: local chunk scan from zero ----
    float h[NS], ap[NS];
    #pragma unroll
    for (int n = 0; n < NS; ++n) { h[n] = 0.f; ap[n] = 1.f; }

    for (int l = 0; l < LC3; l += 2) {
        float d0 = dp[l * DD],        d1 = dp[(l + 1) * DD];
        float u0 = up[l * BB * DD],   u1 = up[(l + 1) * BB * DD];
        float B0[NS], B1[NS];
        LD16(B0, Bp, l * NS);
        LD16(B1, Bp, (l + 1) * NS);
        float du0 = d0 * u0, du1 = d1 * u1;
        #pragma unroll
        for (int n = 0; n < NS; ++n) {
            float dA = exp2f(d0 * a[n]);
            ap[n] *= dA;
            h[n] = fmaf(dA, h[n], du0 * B0[n]);
        }
        #pragma unroll
        for (int n = 0; n < NS; ++n) {
            float dA = exp2f(d1 * a[n]);
            ap[n] *= dA;
            h[n] = fmaf(dA, h[n], du1 * B1[n]);
        }
    }
    #pragma unroll
    for (int n = 0; n < NS; ++n) {
        lap[n * (CH3 * DT3) + c * DT3 + dl] = ap[n];   // consecutive per wave: free
        lhp[n * (CH3 * DT3) + c * DT3 + dl] = h[n];
    }
    __syncthreads();

    // ---- phase B: sequential prefix over chunks (all 512 threads: (dl2, n2)) ----
    {
        int dl2 = tid & 31, n2 = tid >> 5;
        float s = h0[((size_t)b * DD + dt * DT3 + dl2) * NS + n2];
        #pragma unroll 4
        for (int c2 = 0; c2 < CH3; ++c2) {
            int idx = n2 * (CH3 * DT3) + c2 * DT3 + dl2;
            float apv = lap[idx];
            float hpv = lhp[idx];
            lap[idx] = s;                  // in-place: becomes h_in for chunk c2
            s = fmaf(apv, s, hpv);
        }
        h_out[((size_t)b * DD + dt * DT3 + dl2) * NS + n2] = s;
    }
    __syncthreads();

    // ---- phase C: re-scan with true h_in, emit y ----
    #pragma unroll
    for (int n = 0; n < NS; ++n)
        h[n] = lap[n * (CH3 * DT3) + c * DT3 + dl];
    float Dd = Dp[d];
    unsigned short* yp = ybf + ((size_t)b * LL + l0) * DD + d;

    for (int l = 0; l < LC3; l += 2) {
        float d0 = dp[l * DD],        d1 = dp[(l + 1) * DD];
        float u0 = up[l * BB * DD],   u1 = up[(l + 1) * BB * DD];
        float B0[NS], B1[NS], C0[NS], C1[NS];
        LD16(B0, Bp, l * NS);
        LD16(B1, Bp, (l + 1) * NS);
        LD16(C0, Cp, l * NS);
        LD16(C1, Cp, (l + 1) * NS);

        float du0 = d0 * u0, du1 = d1 * u1;
        float acc0 = 0.f, acc1 = 0.f;
        #pragma unroll
        for (int n = 0; n < NS; ++n) {
            float dA = exp2f(d0 * a[n]);
            h[n] = fmaf(dA, h[n], du0 * B0[n]);
            acc0 = fmaf(h[n], C0[n], acc0);
        }
        #pragma unroll
        for (int n = 0; n < NS; ++n) {
            float dA = exp2f(d1 * a[n]);
            h[n] = fmaf(dA, h[n], du1 * B1[n]);
            acc1 = fmaf(h[n], C1[n], acc1);
        }
        yp[l * DD]       = f2bf(fmaf(u0, Dd, acc0));
        yp[(l + 1) * DD] = f2bf(fmaf(u1, Dd, acc1));
    }
}

// ---------------- K3: output projection via bf16 MFMA ----------------
// Out(16384,256) = Y @ W^T.  Block 64x128 (grid 512 = 2/CU), wave 32x64.
__global__ __launch_bounds__(256) void k3_mfma(
    const unsigned short* __restrict__ Ybf,   // (16384,256)
    const unsigned short* __restrict__ Wbf,   // (256,256)
    float* __restrict__ Out)
{
    int wave = threadIdx.x >> 6;
    int lane = threadIdx.x & 63;
    int row0 = (blockIdx.x >> 1) * 64 + (wave >> 1) * 32;
    int col0 = (blockIdx.x & 1) * 128 + (wave & 1) * 64;
    int rl = lane & 15, kb = lane >> 4;

    f32x4 acc[2][4] = {};
    bf16x8 af[2], bf[4], afn[2], bfn[4];

    #pragma unroll
    for (int i = 0; i < 2; ++i)
        af[i] = *reinterpret_cast<const bf16x8*>(&Ybf[(size_t)(row0 + i * 16 + rl) * DD + kb * 8]);
    #pragma unroll
    for (int j = 0; j < 4; ++j)
        bf[j] = *reinterpret_cast<const bf16x8*>(&Wbf[(size_t)(col0 + j * 16 + rl) * DD + kb * 8]);

    #pragma unroll
    for (int ks = 0; ks < 8; ++ks) {
        int kn = (ks + 1) * 32 + kb * 8;
        if (ks < 7) {
            #pragma unroll
            for (int i = 0; i < 2; ++i)
                afn[i] = *reinterpret_cast<const bf16x8*>(&Ybf[(size_t)(row0 + i * 16 + rl) * DD + kn]);
            #pragma unroll
            for (int j = 0; j < 4; ++j)
                bfn[j] = *reinterpret_cast<const bf16x8*>(&Wbf[(size_t)(col0 + j * 16 + rl) * DD + kn]);
        }
        #pragma unroll
        for (int i = 0; i < 2; ++i)
            #pragma unroll
            for (int j = 0; j < 4; ++j)
                acc[i][j] = __builtin_amdgcn_mfma_f32_16x16x32_bf16(af[i], bf[j], acc[i][j], 0, 0, 0);
        #pragma unroll
        for (int i = 0; i < 2; ++i) af[i] = afn[i];
        #pragma unroll
        for (int j = 0; j < 4; ++j) bf[j] = bfn[j];
    }

    // C/D: col = lane&15, row = (lane>>4)*4 + reg
    #pragma unroll
    for (int i = 0; i < 2; ++i)
        #pragma unroll
        for (int j = 0; j < 4; ++j)
            #pragma unroll
            for (int reg = 0; reg < 4; ++reg)
                Out[(size_t)(row0 + i * 16 + kb * 4 + reg) * DD + col0 + j * 16 + rl] = acc[i][j][reg];
}

extern "C" void kernel_launch(void* const* d_in, const int* in_sizes, int n_in,
                              void* d_out, int out_size, void* d_ws, size_t ws_size,
                              hipStream_t stream) {
    const float* pos  = (const float*)d_in[0];   // (L,B,D)
    const float* flow = (const float*)d_in[1];   // (L,B,D)
    const float* h0   = (const float*)d_in[2];   // (B,D,NS)
    const float* xw   = (const float*)d_in[3];   // (48,D)
    const float* dtw  = (const float*)d_in[4];   // (D,16)
    const float* dtb  = (const float*)d_in[5];   // (D)
    const float* alog = (const float*)d_in[6];   // (D,NS)
    const float* dpar = (const float*)d_in[7];   // (D)
    const float* ow   = (const float*)d_in[8];   // (256,256)

    float* out = (float*)d_out;                  // out0: 4,194,304 then h_final: 131,072

    float* ws    = (float*)d_ws;
    float* delta = ws;                           // 4,194,304 floats
    float* Bmw   = ws + 4194304;                 //   262,144
    float* Cmw   = ws + 4456448;                 //   262,144
    unsigned short* ybf = (unsigned short*)(ws + 4718592);   // 16384*256 bf16 = 8 MB
    unsigned short* wbf = (unsigned short*)(ws + 6815744);   // 65536 bf16 = 128 KB
    // total ws usage: ~27.5 MB

    float* h_out = out + 32 * 512 * 256;

    k0_wbf  <<<64,  256, 0, stream>>>(ow, wbf);
    k1_proj <<<512, 256, 0, stream>>>(flow, xw, dtw, dtb, delta, Bmw, Cmw);
    k2_fused<<<256, 512, 65536, stream>>>(pos, h0, alog, dpar, delta, Bmw, Cmw, ybf, h_out);
    k3_mfma <<<512, 256, 0, stream>>>(ybf, wbf, out);
}